// Round 1
// baseline (8462.917 us; speedup 1.0000x reference)
//
#include <hip/hip_runtime.h>
#include <hip/hip_bf16.h>

// Problem constants (match reference)
#define BB 4096
#define TT 256
#define DD 64
#define HH 96
#define G4 384           // 4*H
#define NB 16            // batch rows per block
#define NTHR 192         // 24 col-groups x 8 row-groups
#define KC 40            // K-chunk rows staged in LDS
#define INS 256          // inbuf row stride (floats): [x(64) | h1(96) | h2(96)]

typedef float v4 __attribute__((ext_vector_type(4)));

// ---------------- prep: build k-major concatenated weights in ws ----------------
// W0T[k][j], k in [0,160): k<64 -> Wih0[j][k], else Whh0[j][k-64]
// W1T[k][j], k in [0,192): k<96 -> Wih1[j][k], else Whh1[j][k-96]
__global__ void prep_wt(const float* __restrict__ Wih0, const float* __restrict__ Whh0,
                        const float* __restrict__ Wih1, const float* __restrict__ Whh1,
                        float* __restrict__ W0T, float* __restrict__ W1T) {
    int i = blockIdx.x * blockDim.x + threadIdx.x;
    if (i < 160 * G4) {
        int k = i / G4, j = i % G4;
        W0T[i] = (k < 64) ? Wih0[j * 64 + k] : Whh0[j * 96 + (k - 64)];
    } else {
        int i2 = i - 160 * G4;
        if (i2 < 192 * G4) {
            int k = i2 / G4, j = i2 % G4;
            W1T[i2] = (k < 96) ? Wih1[j * 96 + k] : Whh1[j * 96 + (k - 96)];
        }
    }
}

// async global->LDS copy of nbytes (multiple of 1024), 3 waves
__device__ __forceinline__ void load_chunk(const float* __restrict__ g, float* lds,
                                           int nbytes, int tid) {
    int lane = tid & 63;
    int woff = (tid >> 6) << 10;              // wave * 1024
    const char* gc = (const char*)g;
    char* lc = (char*)lds;
    for (int off = woff; off < nbytes; off += 3 * 1024) {
        __builtin_amdgcn_global_load_lds(
            (const __attribute__((address_space(1))) void*)(gc + off + lane * 16),
            (__attribute__((address_space(3))) void*)(lc + off), 16, 0, 0);
    }
}

__device__ __forceinline__ float sigmoidf_(float x) { return 1.f / (1.f + __expf(-x)); }
__device__ __forceinline__ float tanhf_(float x) {
    float ax = fabsf(x);
    float e = __expf(-2.f * ax);
    float r = (1.f - e) / (1.f + e);
    return copysignf(r, x);
}

// one K-chunk of the gate GEMM: acc[m][g] += in[m][k] * W[k][g*96 + j0 .. +4]
__device__ __forceinline__ void gemm_chunk(v4 (&acc)[2][4], const float* __restrict__ wb,
                                           const float* __restrict__ in0,
                                           const float* __restrict__ in1,
                                           int kc, int j0) {
    #pragma unroll 1
    for (int k4 = 0; k4 < kc; k4 += 4) {
        v4 a0 = *(const v4*)(in0 + k4);
        v4 a1 = *(const v4*)(in1 + k4);
        const float* wr = wb + k4 * G4 + j0;
        #pragma unroll
        for (int kk = 0; kk < 4; ++kk) {
            v4 w0 = *(const v4*)(wr);
            v4 w1 = *(const v4*)(wr + 96);
            v4 w2 = *(const v4*)(wr + 192);
            v4 w3 = *(const v4*)(wr + 288);
            float s0 = a0[kk], s1 = a1[kk];
            acc[0][0] += w0 * s0; acc[0][1] += w1 * s0; acc[0][2] += w2 * s0; acc[0][3] += w3 * s0;
            acc[1][0] += w0 * s1; acc[1][1] += w1 * s1; acc[1][2] += w2 * s1; acc[1][3] += w3 * s1;
            wr += G4;
        }
    }
}

__global__ __launch_bounds__(NTHR) void lstm_main(
    const float* __restrict__ x,
    const float* __restrict__ b0, const float* __restrict__ b1,
    const float* __restrict__ fcW1, const float* __restrict__ fcb1,
    const float* __restrict__ fcW2, const float* __restrict__ fcb2,
    const float* __restrict__ fcW3, const float* __restrict__ fcb3,
    const float* __restrict__ W0T, const float* __restrict__ W1T,
    float* __restrict__ out) {

    __shared__ __align__(16) float inbuf[NB][INS];
    __shared__ __align__(16) float wbuf[2][KC * G4];

    const int tid = threadIdx.x;
    const int ug = tid % 24, rg = tid / 24;   // 24 col-groups x 8 row-groups
    const int r0 = rg * 2, r1 = r0 + 1;
    const int j0 = ug * 4;                    // 4 units per thread
    const int blk = blockIdx.x;
    const float* xblk = x + (size_t)blk * NB * TT * DD;

    // zero h1/h2 regions (cols 64..255)
    for (int i = tid; i < NB * 192; i += NTHR) {
        int r = i / 192, c = i % 192;
        inbuf[r][64 + c] = 0.f;
    }

    // per-thread bias fragments
    v4 b0v[4], b1v[4];
    #pragma unroll
    for (int g = 0; g < 4; ++g) {
        b0v[g] = *(const v4*)&b0[g * 96 + j0];
        b1v[g] = *(const v4*)&b1[g * 96 + j0];
    }

    v4 c1[2] = {0.f, 0.f}, c2[2] = {0.f, 0.f};
    v4 xs0, xs1, xs2, xs3;

    // stage x_0
    if (tid < 64) {
        const float* p = xblk + (size_t)(tid >> 2) * (TT * DD) + (tid & 3) * 16;
        xs0 = *(const v4*)p; xs1 = *(const v4*)(p + 4);
        xs2 = *(const v4*)(p + 8); xs3 = *(const v4*)(p + 12);
        float* q = &inbuf[tid >> 2][(tid & 3) * 16];
        *(v4*)q = xs0; *(v4*)(q + 4) = xs1; *(v4*)(q + 8) = xs2; *(v4*)(q + 12) = xs3;
    }

    // prologue: prefetch L0 chunk 0
    load_chunk(W0T, wbuf[0], KC * G4 * 4, tid);
    __syncthreads();

    int pbuf = 0;
    #pragma unroll 1
    for (int t = 0; t < TT; ++t) {
        v4 acc[2][4];
        #pragma unroll
        for (int g = 0; g < 4; ++g) { acc[0][g] = b0v[g]; acc[1][g] = b0v[g]; }

        // ---- layer 0: K=160 in 4 chunks of 40 ----
        #pragma unroll 1
        for (int c = 0; c < 4; ++c) {
            if (c < 3) load_chunk(W0T + (c + 1) * KC * G4, wbuf[pbuf ^ 1], KC * G4 * 4, tid);
            else       load_chunk(W1T, wbuf[pbuf ^ 1], KC * G4 * 4, tid);
            gemm_chunk(acc, wbuf[pbuf], &inbuf[r0][c * KC], &inbuf[r1][c * KC], KC, j0);
            __syncthreads();
            pbuf ^= 1;
        }

        // elementwise layer 0 (gate order i,f,g,o)
        v4 h1r[2];
        #pragma unroll
        for (int m = 0; m < 2; ++m) {
            #pragma unroll
            for (int q = 0; q < 4; ++q) {
                float vi = sigmoidf_(acc[m][0][q]);
                float vf = sigmoidf_(acc[m][1][q]);
                float vg = tanhf_(acc[m][2][q]);
                float vo = sigmoidf_(acc[m][3][q]);
                float cn = vf * c1[m][q] + vi * vg;
                c1[m][q] = cn;
                h1r[m][q] = vo * tanhf_(cn);
            }
        }
        *(v4*)&inbuf[r0][64 + j0] = h1r[0];
        *(v4*)&inbuf[r1][64 + j0] = h1r[1];
        __syncthreads();

        // ---- layer 1: K=192 in chunks {40,40,40,40,32}, inbuf cols 64..255 ----
        #pragma unroll
        for (int g = 0; g < 4; ++g) { acc[0][g] = b1v[g]; acc[1][g] = b1v[g]; }

        #pragma unroll 1
        for (int c = 0; c < 5; ++c) {
            if (c < 4) {
                int nb = ((c == 3) ? 32 : 40) * G4 * 4;
                load_chunk(W1T + (c + 1) * KC * G4, wbuf[pbuf ^ 1], nb, tid);
            } else {
                load_chunk(W0T, wbuf[pbuf ^ 1], KC * G4 * 4, tid);  // next step's L0 chunk 0
            }
            if (c == 0 && t + 1 < TT && tid < 64) {
                const float* p = xblk + (size_t)(tid >> 2) * (TT * DD) + (size_t)(t + 1) * DD + (tid & 3) * 16;
                xs0 = *(const v4*)p; xs1 = *(const v4*)(p + 4);
                xs2 = *(const v4*)(p + 8); xs3 = *(const v4*)(p + 12);
            }
            int kc = (c == 4) ? 32 : 40;
            gemm_chunk(acc, wbuf[pbuf], &inbuf[r0][64 + c * KC], &inbuf[r1][64 + c * KC], kc, j0);
            if (c == 0 && t + 1 < TT && tid < 64) {
                float* q = &inbuf[tid >> 2][(tid & 3) * 16];
                *(v4*)q = xs0; *(v4*)(q + 4) = xs1; *(v4*)(q + 8) = xs2; *(v4*)(q + 12) = xs3;
            }
            __syncthreads();
            pbuf ^= 1;
        }

        // elementwise layer 1
        v4 h2r[2];
        #pragma unroll
        for (int m = 0; m < 2; ++m) {
            #pragma unroll
            for (int q = 0; q < 4; ++q) {
                float vi = sigmoidf_(acc[m][0][q]);
                float vf = sigmoidf_(acc[m][1][q]);
                float vg = tanhf_(acc[m][2][q]);
                float vo = sigmoidf_(acc[m][3][q]);
                float cn = vf * c2[m][q] + vi * vg;
                c2[m][q] = cn;
                h2r[m][q] = vo * tanhf_(cn);
            }
        }
        *(v4*)&inbuf[r0][160 + j0] = h2r[0];
        *(v4*)&inbuf[r1][160 + j0] = h2r[1];
        __syncthreads();
    }

    // ---------------- MLP head on h2 (inbuf cols 160..255) ----------------
    {
        const int u = tid % 96;
        const int half = tid / 96;  // 0..1
        float* z1 = &wbuf[0][0];            // [16][96]
        float* z2 = z1 + NB * 96;

        const v4* w1r = (const v4*)(fcW1 + u * 96);
        float bb1 = fcb1[u];
        for (int r = half * 8; r < half * 8 + 8; ++r) {
            float s = bb1;
            const v4* hh = (const v4*)&inbuf[r][160];
            #pragma unroll 4
            for (int k4 = 0; k4 < 24; ++k4) {
                v4 w = w1r[k4], h = hh[k4];
                s += w[0] * h[0] + w[1] * h[1] + w[2] * h[2] + w[3] * h[3];
            }
            z1[r * 96 + u] = s > 0.f ? s : 0.01f * s;
        }
        __syncthreads();

        const v4* w2r = (const v4*)(fcW2 + u * 96);
        float bb2 = fcb2[u];
        for (int r = half * 8; r < half * 8 + 8; ++r) {
            float s = bb2;
            const v4* zz = (const v4*)(z1 + r * 96);
            #pragma unroll 4
            for (int k4 = 0; k4 < 24; ++k4) {
                v4 w = w2r[k4], z = zz[k4];
                s += w[0] * z[0] + w[1] * z[1] + w[2] * z[2] + w[3] * z[3];
            }
            z2[r * 96 + u] = s > 0.f ? s : 0.01f * s;
        }
        __syncthreads();

        if (tid < NB) {
            float s = fcb3[0];
            const v4* zz = (const v4*)(z2 + tid * 96);
            const v4* w3 = (const v4*)fcW3;
            #pragma unroll 4
            for (int k4 = 0; k4 < 24; ++k4) {
                v4 w = w3[k4], z = zz[k4];
                s += w[0] * z[0] + w[1] * z[1] + w[2] * z[2] + w[3] * z[3];
            }
            out[blk * NB + tid] = s;
        }
    }
}

extern "C" void kernel_launch(void* const* d_in, const int* in_sizes, int n_in,
                              void* d_out, int out_size, void* d_ws, size_t ws_size,
                              hipStream_t stream) {
    const float* x    = (const float*)d_in[0];
    const float* Wih0 = (const float*)d_in[1];
    const float* Whh0 = (const float*)d_in[2];
    const float* b0   = (const float*)d_in[3];
    const float* Wih1 = (const float*)d_in[4];
    const float* Whh1 = (const float*)d_in[5];
    const float* b1   = (const float*)d_in[6];
    const float* fcW1 = (const float*)d_in[7];
    const float* fcb1 = (const float*)d_in[8];
    const float* fcW2 = (const float*)d_in[9];
    const float* fcb2 = (const float*)d_in[10];
    const float* fcW3 = (const float*)d_in[11];
    const float* fcb3 = (const float*)d_in[12];

    float* W0T = (float*)d_ws;              // 160*384 floats
    float* W1T = W0T + 160 * G4;            // 192*384 floats (total ~540 KB in ws)

    // build transposed weights (135168 elements, 528 blocks x 256 = exact)
    prep_wt<<<528, 256, 0, stream>>>(Wih0, Whh0, Wih1, Whh1, W0T, W1T);

    lstm_main<<<BB / NB, NTHR, 0, stream>>>(x, b0, b1, fcW1, fcb1, fcW2, fcb2,
                                            fcW3, fcb3, W0T, W1T, (float*)d_out);
}

// Round 2
// 1991.509 us; speedup vs baseline: 4.2495x; 4.2495x over previous
//
#include <hip/hip_runtime.h>
#include <hip/hip_bf16.h>

#define TT 256
#define NB 16
#define G4 384
#define NTHR 512

typedef float f32x4 __attribute__((ext_vector_type(4)));
typedef short bf16x8 __attribute__((ext_vector_type(8)));

__device__ __forceinline__ unsigned short f2bf(float f) {
    union { float f; unsigned u; } v; v.f = f;
    unsigned r = (v.u + 0x7FFFu + ((v.u >> 16) & 1u)) >> 16;
    return (unsigned short)r;
}
__device__ __forceinline__ float bf2f(unsigned short h) {
    union { unsigned u; float f; } v; v.u = ((unsigned)h) << 16;
    return v.f;
}
__device__ __forceinline__ float sigf(float x) { return 1.f / (1.f + __expf(-x)); }
__device__ __forceinline__ float tanhf_(float x) {
    float ax = fabsf(x);
    float e = __expf(-2.f * ax);
    float r = (1.f - e) / (1.f + e);
    return copysignf(r, x);
}

#define MFMA(a, b, c) __builtin_amdgcn_mfma_f32_16x16x32_bf16(a, b, c, 0, 0, 0)

// ---------------- prep: build bf16 hi/lo MFMA fragment blocks in ws ----------------
// slot (per plane): layer0: ks*24 + nt (ks 0..4);  layer1: 120 + ks*24 + nt (ks 0..5)
// hi plane slots 0..263, lo plane slots 264..527. Block = 512 ushort (1 KB):
// element e: i = e&7, col = (e>>3)&15, kg = e>>7;  k = ks*32 + kg*8 + i; cg = nt*16+col
// lane l of a wave reads bytes [l*16, l*16+16) -> B-frag: col = l&15, k = ks*32+(l>>4)*8..+7
__global__ void prep_frags(const float* __restrict__ Wih0, const float* __restrict__ Whh0,
                           const float* __restrict__ Wih1, const float* __restrict__ Whh1,
                           unsigned short* __restrict__ wsf) {
    int s = blockIdx.x;        // 0..263
    int e = threadIdx.x;       // 0..511
    int layer = (s >= 120);
    int rem = layer ? s - 120 : s;
    int ks = rem / 24, nt = rem % 24;
    int i = e & 7, col = (e >> 3) & 15, kg = e >> 7;
    int k = ks * 32 + kg * 8 + i;
    int cg = nt * 16 + col;
    float wv;
    if (!layer) wv = (k < 64) ? Wih0[cg * 64 + k] : Whh0[cg * 96 + (k - 64)];
    else        wv = (k < 96) ? Wih1[cg * 96 + k] : Whh1[cg * 96 + (k - 96)];
    unsigned short hi = f2bf(wv);
    float lo = wv - bf2f(hi);
    wsf[s * 512 + e] = hi;
    wsf[(264 + s) * 512 + e] = f2bf(lo);
}

// ---------------- main: 1 block = 16 batch rows, 8 waves, full sequence ----------------
__global__ __launch_bounds__(NTHR, 2) void lstm_main(
    const float* __restrict__ x,
    const float* __restrict__ b0, const float* __restrict__ b1,
    const float* __restrict__ fcW1, const float* __restrict__ fcb1,
    const float* __restrict__ fcW2, const float* __restrict__ fcb2,
    const float* __restrict__ fcW3, const float* __restrict__ fcb3,
    const unsigned short* __restrict__ wsf,
    float* __restrict__ out)
{
    __shared__ unsigned short wlds[120][512];      // L1 lo-plane frags ks1..5 (120 KB), later FC scratch
    __shared__ unsigned short inbuf[2][16][256];   // [plane hi/lo][row][col] XOR-swizzled 16-B units
    __shared__ float gates[G4 * 16];               // col-major [col][row] pre-activations / final h2

    const int tid = threadIdx.x;
    const int lane = tid & 63;
    const int w = tid >> 6;                        // wave 0..7, owns N-tiles 3w..3w+2
    const int blk = blockIdx.x;
    const float* xblk = x + (size_t)blk * NB * TT * 64;

    char* ibp = (char*)&inbuf[0][0][0];
    const char* wldsp = (const char*)&wlds[0][0];

    // ---- persistent register weight fragments ----
    bf16x8 b0h[3][5], b0l[3][5], b1h[3][6];
    bf16x8 b1l00, b1l01, b1l02;
    #pragma unroll
    for (int j = 0; j < 3; ++j) {
        int nt = 3 * w + j;
        #pragma unroll
        for (int ks = 0; ks < 5; ++ks) {
            b0h[j][ks] = *(const bf16x8*)(wsf + (ks * 24 + nt) * 512 + lane * 8);
            b0l[j][ks] = *(const bf16x8*)(wsf + (264 + ks * 24 + nt) * 512 + lane * 8);
        }
        #pragma unroll
        for (int ks = 0; ks < 6; ++ks)
            b1h[j][ks] = *(const bf16x8*)(wsf + (120 + ks * 24 + nt) * 512 + lane * 8);
    }
    b1l00 = *(const bf16x8*)(wsf + (264 + 120 + (3 * w + 0)) * 512 + lane * 8);
    b1l01 = *(const bf16x8*)(wsf + (264 + 120 + (3 * w + 1)) * 512 + lane * 8);
    b1l02 = *(const bf16x8*)(wsf + (264 + 120 + (3 * w + 2)) * 512 + lane * 8);

    const int r_ = lane & 15;            // A-row / C-col within tile
    const int kg_ = lane >> 4;           // k-group / C-row-group
    const int abase = r_ * 512 + ((r_ & 7) << 4);

    float bia00 = b0[(3 * w + 0) * 16 + r_], bia01 = b0[(3 * w + 1) * 16 + r_], bia02 = b0[(3 * w + 2) * 16 + r_];
    float bia10 = b1[(3 * w + 0) * 16 + r_], bia11 = b1[(3 * w + 1) * 16 + r_], bia12 = b1[(3 * w + 2) * 16 + r_];

    // ---- wlds: lo-plane L1 ks1..5 = ws slots 408..527, contiguous 120 KB ----
    {
        const char* src = (const char*)(wsf + 408 * 512);
        char* dst = (char*)&wlds[0][0];
        #pragma unroll 1
        for (int it = 0; it < 15; ++it) {
            int off = (it * 8 + w) * 1024;
            __builtin_amdgcn_global_load_lds(
                (const __attribute__((address_space(1))) void*)(src + off + lane * 16),
                (__attribute__((address_space(3))) void*)(dst + off), 16, 0, 0);
        }
    }

    // zero activation buffer (h regions must start 0)
    {
        int* p = (int*)ibp;
        #pragma unroll 1
        for (int i = tid; i < 4096; i += NTHR) p[i] = 0;
    }
    __syncthreads();

    // stage x_0 (rows 0..15, cols 0..63 hi+lo)
    if (tid < 128) {
        int r = tid >> 3, u16x = tid & 7;
        const float* xp = xblk + (size_t)r * TT * 64 + u16x * 8;
        f32x4 xa = *(const f32x4*)xp, xb = *(const f32x4*)(xp + 4);
        bf16x8 hv, lv;
        #pragma unroll
        for (int q = 0; q < 4; ++q) {
            unsigned short ha = f2bf(xa[q]); hv[q] = (short)ha; lv[q] = (short)f2bf(xa[q] - bf2f(ha));
            unsigned short hb = f2bf(xb[q]); hv[4 + q] = (short)hb; lv[4 + q] = (short)f2bf(xb[q] - bf2f(hb));
        }
        int off = r * 512 + ((u16x ^ (r & 7)) << 4);
        *(bf16x8*)(ibp + off) = hv;
        *(bf16x8*)(ibp + 8192 + off) = lv;
    }
    __syncthreads();

    // elementwise mapping: tid<384: unit eu (0..95), row-group erg (rows erg*4..+3)
    const int eu = tid >> 2, erg = tid & 3;
    f32x4 c1 = {0.f, 0.f, 0.f, 0.f}, c2 = {0.f, 0.f, 0.f, 0.f};
    f32x4 xr_a = {0.f, 0.f, 0.f, 0.f}, xr_b = {0.f, 0.f, 0.f, 0.f};

    const int gw0 = ((3 * w + 0) * 16 + r_) * 16 + kg_ * 4;   // gates write offsets (floats)

    #pragma unroll 1
    for (int t = 0; t < TT; ++t) {
        // prefetch x_{t+1} into regs (waves 6,7) — latency hides under L0 MFMA phase
        if (tid >= 384 && t + 1 < TT) {
            int tt2 = tid - 384, r = tt2 >> 3, u16x = tt2 & 7;
            const float* xp = xblk + (size_t)r * TT * 64 + (size_t)(t + 1) * 64 + u16x * 8;
            xr_a = *(const f32x4*)xp; xr_b = *(const f32x4*)(xp + 4);
        }

        // ===== layer 0 GEMM: A = [x | h1] cols 0..159, K=160 =====
        f32x4 a0 = {bia00, bia00, bia00, bia00};
        f32x4 a1 = {bia01, bia01, bia01, bia01};
        f32x4 a2 = {bia02, bia02, bia02, bia02};
        #pragma unroll
        for (int ks = 0; ks < 5; ++ks) {
            int ao = abase ^ ((ks * 4 + kg_) << 4);
            bf16x8 ah = *(const bf16x8*)(ibp + ao);
            bf16x8 al = *(const bf16x8*)(ibp + 8192 + ao);
            a0 = MFMA(ah, b0h[0][ks], a0); a1 = MFMA(ah, b0h[1][ks], a1); a2 = MFMA(ah, b0h[2][ks], a2);
            a0 = MFMA(al, b0h[0][ks], a0); a1 = MFMA(al, b0h[1][ks], a1); a2 = MFMA(al, b0h[2][ks], a2);
            a0 = MFMA(ah, b0l[0][ks], a0); a1 = MFMA(ah, b0l[1][ks], a1); a2 = MFMA(ah, b0l[2][ks], a2);
        }
        *(f32x4*)(gates + gw0) = a0;
        *(f32x4*)(gates + gw0 + 256) = a1;
        *(f32x4*)(gates + gw0 + 512) = a2;
        __syncthreads();

        // ===== elementwise layer 0 -> h1 (cols 64..159); waves 6,7: stage x_{t+1} =====
        if (tid < 384) {
            const int gr = eu * 16 + erg * 4;
            f32x4 gi = *(const f32x4*)(gates + gr);
            f32x4 gf = *(const f32x4*)(gates + gr + 1536);
            f32x4 gg = *(const f32x4*)(gates + gr + 3072);
            f32x4 go = *(const f32x4*)(gates + gr + 4608);
            const int colel = 64 + eu;
            const int u16c = colel >> 3;
            const int lb2 = (colel & 7) * 2;
            #pragma unroll
            for (int q = 0; q < 4; ++q) {
                float iv = sigf(gi[q]), fv = sigf(gf[q]);
                float gv = tanhf_(gg[q]), ov = sigf(go[q]);
                float cn = fv * c1[q] + iv * gv;
                c1[q] = cn;
                float h = ov * tanhf_(cn);
                unsigned short hh = f2bf(h);
                unsigned short hl = f2bf(h - bf2f(hh));
                int r = erg * 4 + q;
                int off = r * 512 + ((u16c ^ (r & 7)) << 4) + lb2;
                *(unsigned short*)(ibp + off) = hh;
                *(unsigned short*)(ibp + 8192 + off) = hl;
            }
        } else if (t + 1 < TT) {
            int tt2 = tid - 384, r = tt2 >> 3, u16x = tt2 & 7;
            bf16x8 hv, lv;
            #pragma unroll
            for (int q = 0; q < 4; ++q) {
                unsigned short ha = f2bf(xr_a[q]); hv[q] = (short)ha; lv[q] = (short)f2bf(xr_a[q] - bf2f(ha));
                unsigned short hb = f2bf(xr_b[q]); hv[4 + q] = (short)hb; lv[4 + q] = (short)f2bf(xr_b[q] - bf2f(hb));
            }
            int off = r * 512 + ((u16x ^ (r & 7)) << 4);
            *(bf16x8*)(ibp + off) = hv;
            *(bf16x8*)(ibp + 8192 + off) = lv;
        }
        __syncthreads();

        // ===== layer 1 GEMM: A = [h1 | h2] cols 64..255, K=192 =====
        a0 = (f32x4){bia10, bia10, bia10, bia10};
        a1 = (f32x4){bia11, bia11, bia11, bia11};
        a2 = (f32x4){bia12, bia12, bia12, bia12};
        #pragma unroll
        for (int ks = 0; ks < 6; ++ks) {
            int ao = abase ^ ((8 + ks * 4 + kg_) << 4);
            bf16x8 ah = *(const bf16x8*)(ibp + ao);
            bf16x8 al = *(const bf16x8*)(ibp + 8192 + ao);
            a0 = MFMA(ah, b1h[0][ks], a0); a1 = MFMA(ah, b1h[1][ks], a1); a2 = MFMA(ah, b1h[2][ks], a2);
            a0 = MFMA(al, b1h[0][ks], a0); a1 = MFMA(al, b1h[1][ks], a1); a2 = MFMA(al, b1h[2][ks], a2);
            if (ks == 0) {
                a0 = MFMA(ah, b1l00, a0); a1 = MFMA(ah, b1l01, a1); a2 = MFMA(ah, b1l02, a2);
            } else {
                const char* wb = wldsp + (size_t)((ks - 1) * 24) * 1024 + lane * 16;
                bf16x8 bl0 = *(const bf16x8*)(wb + (3 * w + 0) * 1024);
                bf16x8 bl1 = *(const bf16x8*)(wb + (3 * w + 1) * 1024);
                bf16x8 bl2 = *(const bf16x8*)(wb + (3 * w + 2) * 1024);
                a0 = MFMA(ah, bl0, a0); a1 = MFMA(ah, bl1, a1); a2 = MFMA(ah, bl2, a2);
            }
        }
        *(f32x4*)(gates + gw0) = a0;
        *(f32x4*)(gates + gw0 + 256) = a1;
        *(f32x4*)(gates + gw0 + 512) = a2;
        __syncthreads();

        // ===== elementwise layer 1 -> h2 (cols 160..255) + h2 f32 copy into gates[0..1535] =====
        if (tid < 384) {
            const int gr = eu * 16 + erg * 4;
            f32x4 gi = *(const f32x4*)(gates + gr);
            f32x4 gf = *(const f32x4*)(gates + gr + 1536);
            f32x4 gg = *(const f32x4*)(gates + gr + 3072);
            f32x4 go = *(const f32x4*)(gates + gr + 4608);
            const int colel = 160 + eu;
            const int u16c = colel >> 3;
            const int lb2 = (colel & 7) * 2;
            f32x4 hv4;
            #pragma unroll
            for (int q = 0; q < 4; ++q) {
                float iv = sigf(gi[q]), fv = sigf(gf[q]);
                float gv = tanhf_(gg[q]), ov = sigf(go[q]);
                float cn = fv * c2[q] + iv * gv;
                c2[q] = cn;
                float h = ov * tanhf_(cn);
                hv4[q] = h;
                unsigned short hh = f2bf(h);
                unsigned short hl = f2bf(h - bf2f(hh));
                int r = erg * 4 + q;
                int off = r * 512 + ((u16c ^ (r & 7)) << 4) + lb2;
                *(unsigned short*)(ibp + off) = hh;
                *(unsigned short*)(ibp + 8192 + off) = hl;
            }
            // h2 in f32, col-major [unit][row]; safe: this slot is only ever read by this thread
            *(f32x4*)(gates + eu * 16 + erg * 4) = hv4;
        }
        __syncthreads();
    }

    // ---------------- MLP head: h2 = gates[u*16 + r] ----------------
    float* z1 = (float*)&wlds[0][0];   // [16][96]
    float* z2 = z1 + 1536;
    if (tid < 192) {
        int u = tid % 96, half = tid / 96;
        float s0 = fcb1[u];
        for (int r = half * 8; r < half * 8 + 8; ++r) {
            float s = s0;
            #pragma unroll 4
            for (int k = 0; k < 96; ++k) s += fcW1[u * 96 + k] * gates[k * 16 + r];
            z1[r * 96 + u] = s > 0.f ? s : 0.01f * s;
        }
    }
    __syncthreads();
    if (tid < 192) {
        int u = tid % 96, half = tid / 96;
        float s0 = fcb2[u];
        for (int r = half * 8; r < half * 8 + 8; ++r) {
            float s = s0;
            #pragma unroll 4
            for (int k = 0; k < 96; ++k) s += fcW2[u * 96 + k] * z1[r * 96 + k];
            z2[r * 96 + u] = s > 0.f ? s : 0.01f * s;
        }
    }
    __syncthreads();
    if (tid < NB) {
        float s = fcb3[0];
        #pragma unroll 4
        for (int k = 0; k < 96; ++k) s += fcW3[k] * z2[tid * 96 + k];
        out[blk * NB + tid] = s;
    }
}

extern "C" void kernel_launch(void* const* d_in, const int* in_sizes, int n_in,
                              void* d_out, int out_size, void* d_ws, size_t ws_size,
                              hipStream_t stream) {
    const float* x    = (const float*)d_in[0];
    const float* Wih0 = (const float*)d_in[1];
    const float* Whh0 = (const float*)d_in[2];
    const float* b0   = (const float*)d_in[3];
    const float* Wih1 = (const float*)d_in[4];
    const float* Whh1 = (const float*)d_in[5];
    const float* b1   = (const float*)d_in[6];
    const float* fcW1 = (const float*)d_in[7];
    const float* fcb1 = (const float*)d_in[8];
    const float* fcW2 = (const float*)d_in[9];
    const float* fcb2 = (const float*)d_in[10];
    const float* fcW3 = (const float*)d_in[11];
    const float* fcb3 = (const float*)d_in[12];

    unsigned short* wsf = (unsigned short*)d_ws;   // 528 KB of fragment blocks

    prep_frags<<<264, 512, 0, stream>>>(Wih0, Whh0, Wih1, Whh1, wsf);
    lstm_main<<<4096 / NB, NTHR, 0, stream>>>(x, b0, b1, fcW1, fcb1, fcW2, fcb2,
                                              fcW3, fcb3, wsf, (float*)d_out);
}